// Round 5
// baseline (503.744 us; speedup 1.0000x reference)
//
#include <hip/hip_runtime.h>
#include <hip/hip_bf16.h>
#include <stdint.h>

// Problem dims (fixed by setup_inputs)
#define T_DIM 2048
#define I_DIM 4096
#define O_DIM 4096
#define R_DIM 16
#define QBLK  32

typedef __bf16 bf16x8 __attribute__((ext_vector_type(8)));
typedef float  floatx4 __attribute__((ext_vector_type(4)));
typedef unsigned short ushort_t;

#define AS1 __attribute__((address_space(1)))
#define AS3 __attribute__((address_space(3)))

typedef bf16x8 AS3* bf16x8_lds;        // pointer to LDS-resident bf16x8

__device__ __forceinline__ float dot4(float4 a, float4 b) {
  return a.x * b.x + a.y * b.y + a.z * b.z + a.w * b.w;
}

// ---------------- k_xd: xd = alpha * (x @ down^T) ----------------------
// Tiny (256 blocks); reads original inputs, writes 128KB to ws.
__global__ __launch_bounds__(256) void k_xd(const float* __restrict__ x,
                                            const float* __restrict__ down,
                                            const float* __restrict__ alphap,
                                            float* __restrict__ xd) {
  __shared__ float ds[16 * 512];              // 32 KB
  const int b = blockIdx.x, tid = threadIdx.x;
  const int tl = tid >> 5, s = tid & 31;
  const int t = b * 8 + tl;
  float acc[16];
#pragma unroll
  for (int r = 0; r < 16; ++r) acc[r] = 0.f;
  for (int c = 0; c < 8; ++c) {
    const int ib = c * 512;
    __syncthreads();
#pragma unroll
    for (int j = 0; j < 8; ++j) {
      int e = j * 256 + tid;
      int r = e >> 7, col = e & 127;
      ((float4*)ds)[e] = ((const float4*)(down + (size_t)r * I_DIM + ib))[col];
    }
    __syncthreads();
#pragma unroll
    for (int j = 0; j < 4; ++j) {
      float4 xv = ((const float4*)(x + (size_t)t * I_DIM + ib))[s + 32 * j];
#pragma unroll
      for (int r = 0; r < 16; ++r) {
        float4 dv = ((const float4*)ds)[r * 128 + s + 32 * j];
        acc[r] += dot4(xv, dv);
      }
    }
  }
  const float al = alphap[0];
#pragma unroll
  for (int r = 0; r < 16; ++r) {
    float v = acc[r];
    v += __shfl_down(v, 16, 32);
    v += __shfl_down(v, 8, 32);
    v += __shfl_down(v, 4, 32);
    v += __shfl_down(v, 2, 32);
    v += __shfl_down(v, 1, 32);
    if (s == 0) xd[t * 16 + r] = v * al;
  }
}

// ======================= R10 fused GEMM ================================
// R5-R9: four schedules, all 276-362us, MfmaUtil ~10%, all pipes idle ->
// stall-bound on the WORKSPACE data path (prep writes ws at 0.9 TB/s,
// GEMM reads ws 5x below reference structure perf). R10 removes the ws
// round-trip: dequant + bf16-convert fused into the GEMM staging path.
//  - Reads x (f32) and q (int32) + scales DIRECTLY from inputs.
//  - Reg-staged double-buffer (T14 write-late): gload tile kt+1 into
//    VGPRs early; after compute(kt): vmcnt(0), barrier, cvt+ds_write
//    into buf[(kt+1)&1], issue gload(kt+2), lgkm(0), barrier.
//  - Tile 128(T) x 256(O), BK=64, 512 thr / 8 waves (2Mx4N), per-wave
//    64x64 acc[4][4] (math verified R6-R9). LDS 2*(16+32)KB = 96KB.
//  - XOR granule swizzle now applied on the ds_write ADDRESS (reg-staged
//    so write-side swizzle is legal); frag reads identical to R9
//    (R8/R9-verified: 0 bank conflicts).
//  - Dequant: (q-8)*s == fmaf(q, s, -8s) (identical single-rounding);
//    bf16 casts are RNE (same as previous f2bf).

#define BK 64
#define NT (I_DIM / BK)        // 64 K-tiles
#define A_ELEMS (128 * BK)     // 8192  (16KB bf16)
#define B_ELEMS (256 * BK)     // 16384 (32KB bf16)

__device__ __forceinline__ bf16x8 lds_read16(unsigned addr) {
  bf16x8 d;
  asm volatile("ds_read_b128 %0, %1" : "=v"(d) : "v"(addr));
  return d;
}

struct StageRegs {
  float4 ax[2][2];   // A: 2 granules x 2 float4 (16 f32)
  int4   qv[4][2];   // B: 4 granules x 8 int32
  float  sc[4];      // B: per-granule scale
};

__device__ __forceinline__ void gload(StageRegs& R,
                                      const float* __restrict__ x,
                                      const int* __restrict__ q,
                                      const float* __restrict__ scales,
                                      int k0, int tT, int oT, int tid) {
  // A granules: 1024 (128 rows x 8); 2/thread. 8 lanes cover 256B/row.
#pragma unroll
  for (int it = 0; it < 2; ++it) {
    const int e = it * 512 + tid, r = e >> 3, c8 = e & 7;
    const float4* p = (const float4*)(x + (size_t)(tT + r) * I_DIM + k0 + c8 * 8);
    R.ax[it][0] = p[0]; R.ax[it][1] = p[1];
  }
  // B granules: 2048 (256 rows x 8); 4/thread.
#pragma unroll
  for (int it = 0; it < 4; ++it) {
    const int e = it * 512 + tid, r = e >> 3, c8 = e & 7;
    const int4* p = (const int4*)(q + (size_t)(oT + r) * I_DIM + k0 + c8 * 8);
    R.qv[it][0] = p[0]; R.qv[it][1] = p[1];
    R.sc[it] = scales[(size_t)(oT + r) * (I_DIM / QBLK) + ((k0 + c8 * 8) >> 5)];
  }
}

__device__ __forceinline__ void dswrite(const StageRegs& R,
                                        AS3 ushort_t* A0, AS3 ushort_t* B0,
                                        int tid) {
  // Swizzle: granule c8 of row r stored at slot c8 ^ (r&7) (involution;
  // frag reads use the same mapping). Banks: addr = r*128 + g*16 ->
  // uniform coverage, conflict-free b128 writes.
#pragma unroll
  for (int it = 0; it < 2; ++it) {
    const int e = it * 512 + tid, r = e >> 3, c8 = e & 7, g = c8 ^ (r & 7);
    const float4 lo = R.ax[it][0], hi = R.ax[it][1];
    bf16x8 v;
    v[0] = (__bf16)lo.x; v[1] = (__bf16)lo.y; v[2] = (__bf16)lo.z; v[3] = (__bf16)lo.w;
    v[4] = (__bf16)hi.x; v[5] = (__bf16)hi.y; v[6] = (__bf16)hi.z; v[7] = (__bf16)hi.w;
    *(bf16x8_lds)(A0 + (size_t)(r * 8 + g) * 8) = v;
  }
#pragma unroll
  for (int it = 0; it < 4; ++it) {
    const int e = it * 512 + tid, r = e >> 3, c8 = e & 7, g = c8 ^ (r & 7);
    const float s = R.sc[it], n8 = -8.0f * s;
    const int4 q0 = R.qv[it][0], q1 = R.qv[it][1];
    bf16x8 v;
    v[0] = (__bf16)fmaf((float)q0.x, s, n8);
    v[1] = (__bf16)fmaf((float)q0.y, s, n8);
    v[2] = (__bf16)fmaf((float)q0.z, s, n8);
    v[3] = (__bf16)fmaf((float)q0.w, s, n8);
    v[4] = (__bf16)fmaf((float)q1.x, s, n8);
    v[5] = (__bf16)fmaf((float)q1.y, s, n8);
    v[6] = (__bf16)fmaf((float)q1.z, s, n8);
    v[7] = (__bf16)fmaf((float)q1.w, s, n8);
    *(bf16x8_lds)(B0 + (size_t)(r * 8 + g) * 8) = v;
  }
}

__global__ __launch_bounds__(512, 1) void k_fused(const float* __restrict__ x,
                                                  const int* __restrict__ q,
                                                  const float* __restrict__ scales,
                                                  const float* __restrict__ bias,
                                                  const float* __restrict__ xd,
                                                  const float* __restrict__ up,
                                                  float* __restrict__ y) {
  __shared__ __align__(16) ushort_t Ab[2][A_ELEMS];   // 32 KB
  __shared__ __align__(16) ushort_t Bb[2][B_ELEMS];   // 64 KB

  const int tid = threadIdx.x;
  const int lane = tid & 63, wv = tid >> 6;
  const int quad = lane >> 4, m16 = lane & 15;
  const int wm = wv >> 2, wn = wv & 3;

  const int oT = blockIdx.x * 256, tT = blockIdx.y * 128;

  const unsigned aL = (unsigned)(uintptr_t)(AS3 ushort_t*)&Ab[0][0];
  const unsigned bL = (unsigned)(uintptr_t)(AS3 ushort_t*)&Bb[0][0];

  floatx4 acc[4][4] = {};
  StageRegs R;

  // Prologue: tile0 -> regs -> LDS buf0; tile1 -> regs (in flight).
  gload(R, x, q, scales, 0, tT, oT, tid);
  asm volatile("s_waitcnt vmcnt(0)" ::: "memory");
  __builtin_amdgcn_sched_barrier(0);
  dswrite(R, (AS3 ushort_t*)&Ab[0][0], (AS3 ushort_t*)&Bb[0][0], tid);
  gload(R, x, q, scales, BK, tT, oT, tid);
  asm volatile("s_waitcnt lgkmcnt(0)" ::: "memory");
  __builtin_amdgcn_sched_barrier(0);
  __builtin_amdgcn_s_barrier();

  for (int kt = 0; kt < NT; ++kt) {
    const int cur = kt & 1;
    const unsigned aB = aL + (unsigned)cur * (A_ELEMS * 2);
    const unsigned bB = bL + (unsigned)cur * (B_ELEMS * 2);

    bf16x8 a0[4], b0[4], a1[4], b1[4];
#pragma unroll
    for (int i = 0; i < 4; ++i) {
      const int m = wm * 64 + i * 16 + m16;
      a0[i] = lds_read16(aB + (unsigned)((m * 8 + (quad ^ (m & 7))) * 16));
    }
#pragma unroll
    for (int i = 0; i < 4; ++i) {
      const int n = wn * 64 + i * 16 + m16;
      b0[i] = lds_read16(bB + (unsigned)((n * 8 + (quad ^ (n & 7))) * 16));
    }
#pragma unroll
    for (int i = 0; i < 4; ++i) {
      const int m = wm * 64 + i * 16 + m16;
      a1[i] = lds_read16(aB + (unsigned)((m * 8 + ((4 + quad) ^ (m & 7))) * 16));
    }
#pragma unroll
    for (int i = 0; i < 4; ++i) {
      const int n = wn * 64 + i * 16 + m16;
      b1[i] = lds_read16(bB + (unsigned)((n * 8 + ((4 + quad) ^ (n & 7))) * 16));
    }
    asm volatile("s_waitcnt lgkmcnt(8)" ::: "memory");   // a0/b0 ready
    __builtin_amdgcn_sched_barrier(0);
    __builtin_amdgcn_s_setprio(1);
#pragma unroll
    for (int i = 0; i < 4; ++i)
#pragma unroll
      for (int j = 0; j < 4; ++j)
        acc[i][j] = __builtin_amdgcn_mfma_f32_16x16x32_bf16(a0[i], b0[j], acc[i][j], 0, 0, 0);
    __builtin_amdgcn_s_setprio(0);
    asm volatile("s_waitcnt lgkmcnt(0)" ::: "memory");   // a1/b1 ready
    __builtin_amdgcn_sched_barrier(0);
    __builtin_amdgcn_s_setprio(1);
#pragma unroll
    for (int i = 0; i < 4; ++i)
#pragma unroll
      for (int j = 0; j < 4; ++j)
        acc[i][j] = __builtin_amdgcn_mfma_f32_16x16x32_bf16(a1[i], b1[j], acc[i][j], 0, 0, 0);
    __builtin_amdgcn_s_setprio(0);

    if (kt < NT - 1) {
      // Regs for tile kt+1 were issued one tile ago -> ~free wait.
      asm volatile("s_waitcnt vmcnt(0)" ::: "memory");
      __builtin_amdgcn_sched_barrier(0);
      __builtin_amdgcn_s_barrier();      // all waves done reading buf[cur^1]
      dswrite(R, (AS3 ushort_t*)&Ab[cur ^ 1][0], (AS3 ushort_t*)&Bb[cur ^ 1][0], tid);
      if (kt < NT - 2)
        gload(R, x, q, scales, (kt + 2) * BK, tT, oT, tid);
      asm volatile("s_waitcnt lgkmcnt(0)" ::: "memory"); // ds_writes landed
      __builtin_amdgcn_sched_barrier(0);
      __builtin_amdgcn_s_barrier();
    }
  }

  // Epilogue: y[t][o] = acc + dot16(xd[t], up[o]) + bias[o]
  // C/D layout: row = quad*4+reg, col = lane&15 (m89-verified).
#pragma unroll
  for (int im = 0; im < 4; ++im) {
#pragma unroll
    for (int reg = 0; reg < 4; ++reg) {
      const int t = tT + wm * 64 + im * 16 + quad * 4 + reg;
      const float4* xr = (const float4*)(xd + t * 16);
      float4 x0 = xr[0], x1 = xr[1], x2 = xr[2], x3 = xr[3];
#pragma unroll
      for (int in_ = 0; in_ < 4; ++in_) {
        const int o = oT + wn * 64 + in_ * 16 + m16;
        const float4* ur = (const float4*)(up + (size_t)o * R_DIM);
        float lv = dot4(x0, ur[0]) + dot4(x1, ur[1]) +
                   dot4(x2, ur[2]) + dot4(x3, ur[3]);
        y[(size_t)t * O_DIM + o] = acc[im][in_][reg] + lv + bias[o];
      }
    }
  }
}

extern "C" void kernel_launch(void* const* d_in, const int* in_sizes, int n_in,
                              void* d_out, int out_size, void* d_ws, size_t ws_size,
                              hipStream_t stream) {
  const float* x      = (const float*)d_in[0];
  const int*   q      = (const int*)d_in[1];
  const float* scales = (const float*)d_in[2];
  const float* up     = (const float*)d_in[3];
  const float* down   = (const float*)d_in[4];
  const float* alpha  = (const float*)d_in[5];
  const float* bias   = (const float*)d_in[6];
  float* y = (float*)d_out;

  // ws layout: xd f32 [T,16] only (128 KB)
  float* xd = (float*)d_ws;

  hipLaunchKernelGGL(k_xd, dim3(256), dim3(256), 0, stream, x, down, alpha, xd);
  hipLaunchKernelGGL(k_fused, dim3(O_DIM / 256, T_DIM / 128), dim3(512), 0, stream,
                     x, q, scales, bias, xd, up, y);
}

// Round 6
// 430.382 us; speedup vs baseline: 1.1705x; 1.1705x over previous
//
#include <hip/hip_runtime.h>
#include <hip/hip_bf16.h>
#include <stdint.h>

// Problem dims (fixed by setup_inputs)
#define T_DIM 2048
#define I_DIM 4096
#define O_DIM 4096
#define R_DIM 16
#define QBLK  32

typedef __bf16 bf16x8 __attribute__((ext_vector_type(8)));
typedef float  floatx4 __attribute__((ext_vector_type(4)));
typedef unsigned short ushort_t;

#define AS1 __attribute__((address_space(1)))
#define AS3 __attribute__((address_space(3)))

__device__ __forceinline__ ushort_t f2bf(float f) {
  unsigned u = __float_as_uint(f);
  u += 0x7FFFu + ((u >> 16) & 1u);   // round-to-nearest-even
  return (ushort_t)(u >> 16);
}

__device__ __forceinline__ float dot4(float4 a, float4 b) {
  return a.x * b.x + a.y * b.y + a.z * b.z + a.w * b.w;
}

// ---------------- k_stream: xb=bf16(x) | wb=dequant(q). ZERO LDS. ------
__global__ __launch_bounds__(256) void k_stream(const float* __restrict__ x,
                                                const int* __restrict__ q,
                                                const float* __restrict__ scales,
                                                ushort_t* __restrict__ xb,
                                                ushort_t* __restrict__ wb) {
  const int b = blockIdx.x, tid = threadIdx.x;
  if (b < 4096) {                             // ---- prep_x
    int idx = b * 256 + tid;                  // 8-element chunk id
    const float4* xp = (const float4*)x;
    float4 a = xp[idx * 2], c = xp[idx * 2 + 1];
    union { ushort_t u[8]; uint4 v; } r;
    r.u[0] = f2bf(a.x); r.u[1] = f2bf(a.y); r.u[2] = f2bf(a.z); r.u[3] = f2bf(a.w);
    r.u[4] = f2bf(c.x); r.u[5] = f2bf(c.y); r.u[6] = f2bf(c.z); r.u[7] = f2bf(c.w);
    ((uint4*)xb)[idx] = r.v;
    return;
  }
  {                                           // ---- prep_w
    int idx = (b - 4096) * 256 + tid;
    int o  = idx >> 9;
    int i0 = (idx & 511) * 8;
    float s = scales[o * (I_DIM / QBLK) + (i0 >> 5)];
    const int4* qp = (const int4*)(q + (size_t)o * I_DIM + i0);
    int4 q0 = qp[0], q1 = qp[1];
    union { ushort_t u[8]; uint4 v; } r;
    r.u[0] = f2bf((float)(q0.x - 8) * s); r.u[1] = f2bf((float)(q0.y - 8) * s);
    r.u[2] = f2bf((float)(q0.z - 8) * s); r.u[3] = f2bf((float)(q0.w - 8) * s);
    r.u[4] = f2bf((float)(q1.x - 8) * s); r.u[5] = f2bf((float)(q1.y - 8) * s);
    r.u[6] = f2bf((float)(q1.z - 8) * s); r.u[7] = f2bf((float)(q1.w - 8) * s);
    ((uint4*)wb)[idx] = r.v;
  }
}

// ---------------- k_xd: xd = alpha * (x @ down^T) ----------------------
__global__ __launch_bounds__(256) void k_xd(const float* __restrict__ x,
                                            const float* __restrict__ down,
                                            const float* __restrict__ alphap,
                                            float* __restrict__ xd) {
  __shared__ float ds[16 * 512];              // 32 KB
  const int b = blockIdx.x, tid = threadIdx.x;
  const int tl = tid >> 5, s = tid & 31;
  const int t = b * 8 + tl;
  float acc[16];
#pragma unroll
  for (int r = 0; r < 16; ++r) acc[r] = 0.f;
  for (int c = 0; c < 8; ++c) {
    const int ib = c * 512;
    __syncthreads();
#pragma unroll
    for (int j = 0; j < 8; ++j) {
      int e = j * 256 + tid;
      int r = e >> 7, col = e & 127;
      ((float4*)ds)[e] = ((const float4*)(down + (size_t)r * I_DIM + ib))[col];
    }
    __syncthreads();
#pragma unroll
    for (int j = 0; j < 4; ++j) {
      float4 xv = ((const float4*)(x + (size_t)t * I_DIM + ib))[s + 32 * j];
#pragma unroll
      for (int r = 0; r < 16; ++r) {
        float4 dv = ((const float4*)ds)[r * 128 + s + 32 * j];
        acc[r] += dot4(xv, dv);
      }
    }
  }
  const float al = alphap[0];
#pragma unroll
  for (int r = 0; r < 16; ++r) {
    float v = acc[r];
    v += __shfl_down(v, 16, 32);
    v += __shfl_down(v, 8, 32);
    v += __shfl_down(v, 4, 32);
    v += __shfl_down(v, 2, 32);
    v += __shfl_down(v, 1, 32);
    if (s == 0) xd[t * 16 + r] = v * al;
  }
}

// ======================= R11 main GEMM =================================
// R5-R10 invariant found: every schedule saturates ~3 TB/s of L2-miss
// operand traffic (re-read panels served by Infinity Cache; FETCH_SIZE
// shows HBM sees ~none of it). Plain 2D grid round-robins blocks over
// XCDs -> per-XCD L2 sees ~32 unrelated panels -> 0 reuse -> ALL
// 768 MB of re-reads cross the L3 fabric. R11 = R9 kernel VERBATIM with
// ONE change: XCD-affinity block mapping. XCD x (= id&7, the HW
// round-robin) owns bx in {2x,2x+1} x all 16 by. Its 32 co-resident
// blocks share a ~1 MB K-frontier (16 A-slices + 2 B-slices) << 4 MB L2
// -> each byte read from L3 once per XCD: 32 + 8*16 = ~160 MB (4.8x cut).
// Everything else identical to R9 (276us best): BM=128 x BN=256, BK=64,
// 512 thr / 8 waves, ring-3 LDS 144KB, one barrier/tile, vmcnt(6),
// lgkm(8) split, XOR swizzle, asm ds_read + rule-18 fences, setprio.

#define BK 64
#define NT (I_DIM / BK)        // 64 K-tiles
#define ASZ (128 * BK)         // A tile elems (16KB)
#define BSZ (256 * BK)         // B tile elems (32KB)

__device__ __forceinline__ bf16x8 lds_read16(unsigned addr) {
  bf16x8 d;
  asm volatile("ds_read_b128 %0, %1" : "=v"(d) : "v"(addr));
  return d;
}

__device__ __forceinline__ void stage6(const ushort_t* __restrict__ ga,
                                       const ushort_t* __restrict__ gb,
                                       ushort_t* Ast, ushort_t* Bst, int tid) {
  // A: 128x64 bf16 = 1024 granules -> 2/thread; B: 256x64 = 2048 -> 4/thread.
  // LDS dest linear; global granule pre-swizzled with involution g^(r&7).
#pragma unroll
  for (int it = 0; it < 2; ++it) {
    const int seg = it * 512 + tid;
    const int r = seg >> 3, cg = (seg & 7) ^ (r & 7);
    __builtin_amdgcn_global_load_lds(
        (const AS1 char*)(ga + (size_t)r * I_DIM + cg * 8),
        (AS3 char*)(Ast + (size_t)seg * 8), 16, 0, 0);
  }
#pragma unroll
  for (int it = 0; it < 4; ++it) {
    const int seg = it * 512 + tid;
    const int r = seg >> 3, cg = (seg & 7) ^ (r & 7);
    __builtin_amdgcn_global_load_lds(
        (const AS1 char*)(gb + (size_t)r * I_DIM + cg * 8),
        (AS3 char*)(Bst + (size_t)seg * 8), 16, 0, 0);
  }
}

// One K-tile. VM: vmcnt at tile end (6 steady / 0 / -1 none). STG: stage kt+2.
template<int VM, bool STG>
__device__ __forceinline__ void ktile(unsigned aB, unsigned bB,
                                      ushort_t* Ast, ushort_t* Bst,
                                      const ushort_t* ga, const ushort_t* gb,
                                      floatx4 (&acc)[4][4], int tid) {
  const int lane = tid & 63, wv = tid >> 6;
  const int quad = lane >> 4, m16 = lane & 15;
  const int wm = wv >> 2, wn = wv & 3;

  if constexpr (STG) stage6(ga, gb, Ast, Bst, tid);

  bf16x8 a0[4], b0[4], a1[4], b1[4];
#pragma unroll
  for (int i = 0; i < 4; ++i) {
    const int m = wm * 64 + i * 16 + m16;
    a0[i] = lds_read16(aB + (unsigned)((m * 8 + (quad ^ (m & 7))) * 16));
  }
#pragma unroll
  for (int i = 0; i < 4; ++i) {
    const int n = wn * 64 + i * 16 + m16;
    b0[i] = lds_read16(bB + (unsigned)((n * 8 + (quad ^ (n & 7))) * 16));
  }
#pragma unroll
  for (int i = 0; i < 4; ++i) {
    const int m = wm * 64 + i * 16 + m16;
    a1[i] = lds_read16(aB + (unsigned)((m * 8 + ((4 + quad) ^ (m & 7))) * 16));
  }
#pragma unroll
  for (int i = 0; i < 4; ++i) {
    const int n = wn * 64 + i * 16 + m16;
    b1[i] = lds_read16(bB + (unsigned)((n * 8 + ((4 + quad) ^ (n & 7))) * 16));
  }
  // half0 frags (first 8 ds_reads, in-order retire) ready:
  asm volatile("s_waitcnt lgkmcnt(8)" ::: "memory");
  __builtin_amdgcn_sched_barrier(0);
  __builtin_amdgcn_s_setprio(1);
#pragma unroll
  for (int i = 0; i < 4; ++i)
#pragma unroll
    for (int j = 0; j < 4; ++j)
      acc[i][j] = __builtin_amdgcn_mfma_f32_16x16x32_bf16(a0[i], b0[j], acc[i][j], 0, 0, 0);
  __builtin_amdgcn_s_setprio(0);
  asm volatile("s_waitcnt lgkmcnt(0)" ::: "memory");
  __builtin_amdgcn_sched_barrier(0);
  __builtin_amdgcn_s_setprio(1);
#pragma unroll
  for (int i = 0; i < 4; ++i)
#pragma unroll
    for (int j = 0; j < 4; ++j)
      acc[i][j] = __builtin_amdgcn_mfma_f32_16x16x32_bf16(a1[i], b1[j], acc[i][j], 0, 0, 0);
  __builtin_amdgcn_s_setprio(0);
  if constexpr (VM == 6)      asm volatile("s_waitcnt vmcnt(6)" ::: "memory");
  else if constexpr (VM == 0) asm volatile("s_waitcnt vmcnt(0)" ::: "memory");
  if constexpr (VM >= 0) __builtin_amdgcn_sched_barrier(0);
  __builtin_amdgcn_s_barrier();
}

__global__ __launch_bounds__(512, 2) void k_gemm(const ushort_t* __restrict__ xb,
                                                 const ushort_t* __restrict__ wb,
                                                 const float* __restrict__ bias,
                                                 const float* __restrict__ xd,
                                                 const float* __restrict__ up,
                                                 float* __restrict__ y) {
  __shared__ __align__(16) ushort_t As[3][ASZ];   // 48 KB
  __shared__ __align__(16) ushort_t Bs[3][BSZ];   // 96 KB

  const int tid = threadIdx.x;

  // R11 XCD-affinity mapping (the ONLY change vs R9):
  // id&7 = XCD (HW round-robin); slot = id>>3 in [0,32).
  // XCD x owns bx in {2x, 2x+1}; by = slot>>1. Bijective.
  const int id = blockIdx.x;
  const int xcd = id & 7, slot = id >> 3;
  const int bx = xcd * 2 + (slot & 1);      // O tile [0,16)
  const int by = slot >> 1;                 // T tile [0,16)
  const int oT = bx * 256, tT = by * 128;

  const ushort_t* ap = xb + (size_t)tT * I_DIM;
  const ushort_t* bp = wb + (size_t)oT * I_DIM;

  const unsigned aL = (unsigned)(uintptr_t)(AS3 ushort_t*)&As[0][0];
  const unsigned bL = (unsigned)(uintptr_t)(AS3 ushort_t*)&Bs[0][0];
  const unsigned aS0 = aL, aS1 = aL + ASZ * 2, aS2 = aL + ASZ * 4;
  const unsigned bS0 = bL, bS1 = bL + BSZ * 2, bS2 = bL + BSZ * 4;

  floatx4 acc[4][4] = {};

  // Prologue: stage tiles 0,1 (12 loads/thread); wait tile 0 (vmcnt 6).
  stage6(ap, bp, As[0], Bs[0], tid);
  stage6(ap + BK, bp + BK, As[1], Bs[1], tid);
  asm volatile("s_waitcnt vmcnt(6)" ::: "memory");
  __builtin_amdgcn_sched_barrier(0);
  __builtin_amdgcn_s_barrier();

  // Main loop: kt = 0..59 in triples (slots kt%3); stage kt+2.
  int kc = 2 * BK;
  for (int g = 0; g < 20; ++g) {
    ktile<6, true>(aS0, bS0, As[2], Bs[2], ap + kc, bp + kc, acc, tid); kc += BK;
    ktile<6, true>(aS1, bS1, As[0], Bs[0], ap + kc, bp + kc, acc, tid); kc += BK;
    ktile<6, true>(aS2, bS2, As[1], Bs[1], ap + kc, bp + kc, acc, tid); kc += BK;
  }
  // kt=60 (slot0, stage t62->slot2), kt=61 (slot1, stage t63->slot0)
  ktile<6, true>(aS0, bS0, As[2], Bs[2], ap + kc, bp + kc, acc, tid); kc += BK;
  ktile<6, true>(aS1, bS1, As[0], Bs[0], ap + kc, bp + kc, acc, tid);
  // kt=62 (slot2, drain t63), kt=63 (slot0)
  ktile<0, false>(aS2, bS2, nullptr, nullptr, nullptr, nullptr, acc, tid);
  ktile<-1, false>(aS0, bS0, nullptr, nullptr, nullptr, nullptr, acc, tid);

  // Epilogue: y[t][o] = acc + dot16(xd[t], up[o]) + bias[o]
  // C/D layout: row = quad*4+reg, col = lane&15 (m89-verified).
  const int lane = tid & 63, wv = tid >> 6;
  const int quad = lane >> 4, m16 = lane & 15;
  const int wm = wv >> 2, wn = wv & 3;
#pragma unroll
  for (int im = 0; im < 4; ++im) {
#pragma unroll
    for (int reg = 0; reg < 4; ++reg) {
      const int t = tT + wm * 64 + im * 16 + quad * 4 + reg;
      const float4* xr = (const float4*)(xd + t * 16);
      float4 x0 = xr[0], x1 = xr[1], x2 = xr[2], x3 = xr[3];
#pragma unroll
      for (int in_ = 0; in_ < 4; ++in_) {
        const int o = oT + wn * 64 + in_ * 16 + m16;
        const float4* ur = (const float4*)(up + (size_t)o * R_DIM);
        float lv = dot4(x0, ur[0]) + dot4(x1, ur[1]) +
                   dot4(x2, ur[2]) + dot4(x3, ur[3]);
        y[(size_t)t * O_DIM + o] = acc[im][in_][reg] + lv + bias[o];
      }
    }
  }
}

extern "C" void kernel_launch(void* const* d_in, const int* in_sizes, int n_in,
                              void* d_out, int out_size, void* d_ws, size_t ws_size,
                              hipStream_t stream) {
  const float* x      = (const float*)d_in[0];
  const int*   q      = (const int*)d_in[1];
  const float* scales = (const float*)d_in[2];
  const float* up     = (const float*)d_in[3];
  const float* down   = (const float*)d_in[4];
  const float* alpha  = (const float*)d_in[5];
  const float* bias   = (const float*)d_in[6];
  float* y = (float*)d_out;

  // ws layout: xb bf16 [T,I] (16 MB) | wb bf16 [O,I] (32 MB) | xd f32 [T,16]
  ushort_t* xb = (ushort_t*)d_ws;
  ushort_t* wb = (ushort_t*)((char*)d_ws + (size_t)T_DIM * I_DIM * 2);
  float*    xd = (float*)((char*)d_ws + (size_t)T_DIM * I_DIM * 2 + (size_t)O_DIM * I_DIM * 2);

  hipLaunchKernelGGL(k_stream, dim3(4096 + 8192), dim3(256), 0, stream,
                     x, q, scales, xb, wb);
  hipLaunchKernelGGL(k_xd, dim3(256), dim3(256), 0, stream, x, down, alpha, xd);
  hipLaunchKernelGGL(k_gemm, dim3((O_DIM / 256) * (T_DIM / 128)), dim3(512), 0, stream,
                     xb, wb, bias, xd, up, y);
}